// Round 1
// baseline (200.285 us; speedup 1.0000x reference)
//
#include <hip/hip_runtime.h>

#define BATCH 50
#define MAX_ATOMS 21000
#define DIM 128
#define ROW4 (DIM / 4)   // 32 float4 per feature row

// Kernel 1: compute starts[b] = lower_bound(idx, b) for b in [0, BATCH],
// so counts[b] = starts[b+1]-starts[b]. Handles both int32 and int64 index
// storage (detected in-kernel: int64 little-endian small values viewed as
// int32 produce a strictly descending pair [v,0] somewhere mid-array).
__global__ void compute_starts_kernel(const int* __restrict__ idx32, int N,
                                      int* __restrict__ starts) {
    __shared__ int s_is64;
    if (threadIdx.x == 0) {
        int flag = 0;
        int base = N / 2;
        int lim = N - 1;
        for (int k = 0; k < 256 && (base + k + 1) <= lim; ++k) {
            if (idx32[base + k] > idx32[base + k + 1]) { flag = 1; break; }
        }
        s_is64 = flag;
    }
    __syncthreads();
    const int stride = s_is64 ? 2 : 1;

    int b = threadIdx.x;
    if (b <= BATCH) {
        // first i in [0,N) with idx[i] >= b
        int lo = 0, hi = N;
        while (lo < hi) {
            int mid = (lo + hi) >> 1;
            int v = idx32[(long)mid * stride];  // low word == value (0..49)
            if (v < b) lo = mid + 1; else hi = mid;
        }
        starts[b] = lo;
    }
}

// Kernel 2: gather-style padded write. One thread = one float4 of output.
// out[b][p][q4] = (p < count[b]) ? feat[(starts[b]+p)*ROW4 + q4] : 0
__global__ __launch_bounds__(256) void gather_pad_kernel(
        const float4* __restrict__ feat,
        const int* __restrict__ starts,
        float4* __restrict__ out) {
    unsigned int gid = blockIdx.x * 256u + threadIdx.x;
    const unsigned int total4 = (unsigned int)BATCH * MAX_ATOMS * ROW4;  // 33.6M
    if (gid >= total4) return;

    unsigned int q   = gid & (ROW4 - 1);   // float4 index within row
    unsigned int row = gid >> 5;           // b * MAX_ATOMS + p
    unsigned int b   = row / MAX_ATOMS;    // magic-mul div by constant
    unsigned int p   = row - b * MAX_ATOMS;

    int s   = starts[b];
    int cnt = starts[b + 1] - s;

    float4 v = make_float4(0.f, 0.f, 0.f, 0.f);
    if ((int)p < cnt) {
        v = feat[(long)(s + (int)p) * ROW4 + q];
    }
    out[gid] = v;
}

extern "C" void kernel_launch(void* const* d_in, const int* in_sizes, int n_in,
                              void* d_out, int out_size, void* d_ws, size_t ws_size,
                              hipStream_t stream) {
    const float* feat = (const float*)d_in[0];
    const int*   idx  = (const int*)d_in[1];
    int N = in_sizes[1];                    // 1,000,000 atoms

    int* starts = (int*)d_ws;               // BATCH+1 ints of scratch

    compute_starts_kernel<<<1, 64, 0, stream>>>(idx, N, starts);

    const long total4 = (long)BATCH * MAX_ATOMS * ROW4;  // 33,600,000
    const int  block  = 256;
    const int  grid   = (int)((total4 + block - 1) / block);
    gather_pad_kernel<<<grid, block, 0, stream>>>(
        (const float4*)feat, starts, (float4*)d_out);
}

// Round 2
// 182.228 us; speedup vs baseline: 1.0991x; 1.0991x over previous
//
#include <hip/hip_runtime.h>

#define BATCH 50
#define MAX_ATOMS 21000
#define DIM 128
#define ROW4 (DIM / 4)            // 32 float4 per feature row
#define TOTAL4 (BATCH * MAX_ATOMS * ROW4)  // 33,600,000 float4 outputs
#define SAMPLES 1024

typedef float f4 __attribute__((ext_vector_type(4)));

// Kernel 1: starts[b] = lower_bound(idx, b) for b in [0, BATCH].
// Hierarchical: wave-0 detects int32-vs-int64 storage, 1024 threads sample
// idx into LDS (one parallel HBM round-trip), then 51 threads binary-search
// a <= step-wide bracket (few serial misses instead of ~20).
__global__ __launch_bounds__(1024) void compute_starts_kernel(
        const int* __restrict__ idx32, int N, int* __restrict__ starts) {
    __shared__ int s_flag;
    __shared__ int samp[SAMPLES];

    // int64 detection: sorted int64 little-endian viewed as int32 gives
    // [v,0,v,0,...] -> a descending adjacent pair near the middle.
    if (threadIdx.x < 64) {
        int base = N / 2;
        int a = idx32[base + threadIdx.x];
        int c = idx32[base + threadIdx.x + 1];
        unsigned long long m = __ballot(a > c);
        if (threadIdx.x == 0) s_flag = (m != 0ull) ? 1 : 0;
    }
    __syncthreads();
    const int stride = s_flag ? 2 : 1;   // word stride to the value word
    const int step = (N + SAMPLES - 1) / SAMPLES;

    {   // coarse sampling
        int t = threadIdx.x;
        int i = t * step; if (i > N - 1) i = N - 1;
        samp[t] = idx32[(long)i * stride];
    }
    __syncthreads();

    int b = threadIdx.x;
    if (b <= BATCH) {
        // coarse: first sample index u with samp[u] >= b (u in [0, SAMPLES])
        int ulo = 0, uhi = SAMPLES;
        while (ulo < uhi) {
            int m = (ulo + uhi) >> 1;
            if (samp[m] < b) ulo = m + 1; else uhi = m;
        }
        int lo, hi;
        if (ulo == 0) { lo = 0; hi = 1; }
        else {
            int j = (ulo - 1) * step; if (j > N - 1) j = N - 1;
            lo = j + 1;
            if (ulo == SAMPLES) hi = N;
            else { int k = ulo * step; if (k > N - 1) k = N - 1; hi = k + 1; }
        }
        // fine: lower_bound within [lo, hi)
        while (lo < hi) {
            int m = (lo + hi) >> 1;
            if (idx32[(long)m * stride] < b) lo = m + 1; else hi = m;
        }
        starts[b] = lo;
    }
}

// Kernel 2: gather-style padded write, 4 float4 per thread, NT streams.
// out[b][p][q] = (p < count[b]) ? feat[(starts[b]+p)*ROW4 + q] : 0
__global__ __launch_bounds__(256) void gather_pad_kernel(
        const f4* __restrict__ feat,
        const int* __restrict__ starts,
        f4* __restrict__ out) {
    __shared__ int s_starts[BATCH + 1];
    if (threadIdx.x <= BATCH) s_starts[threadIdx.x] = starts[threadIdx.x];
    __syncthreads();

    unsigned int base = blockIdx.x * 1024u + threadIdx.x;
#pragma unroll
    for (int k = 0; k < 4; ++k) {
        unsigned int gid = base + (unsigned)k * 256u;
        if (gid < (unsigned)TOTAL4) {
            unsigned int q   = gid & (ROW4 - 1);
            unsigned int row = gid >> 5;              // b * MAX_ATOMS + p
            unsigned int b   = row / MAX_ATOMS;       // magic-mul
            unsigned int p   = row - b * MAX_ATOMS;
            int s = s_starts[b];
            int e = s_starts[b + 1];
            f4 v = (f4)(0.0f);
            if ((int)p < e - s)
                v = __builtin_nontemporal_load(feat + (long)(s + (int)p) * ROW4 + q);
            __builtin_nontemporal_store(v, out + gid);
        }
    }
}

extern "C" void kernel_launch(void* const* d_in, const int* in_sizes, int n_in,
                              void* d_out, int out_size, void* d_ws, size_t ws_size,
                              hipStream_t stream) {
    const float* feat = (const float*)d_in[0];
    const int*   idx  = (const int*)d_in[1];
    int N = in_sizes[1];                    // 1,000,000 atoms

    int* starts = (int*)d_ws;               // BATCH+1 ints of scratch

    compute_starts_kernel<<<1, 1024, 0, stream>>>(idx, N, starts);

    const int grid = (TOTAL4 + 1023) / 1024;   // 4 float4 per thread
    gather_pad_kernel<<<grid, 256, 0, stream>>>(
        (const f4*)feat, starts, (f4*)d_out);
}